// Round 1
// baseline (404.597 us; speedup 1.0000x reference)
//
#include <hip/hip_runtime.h>
#include <hip/hip_bf16.h>

typedef __attribute__((ext_vector_type(4))) float floatx4;
typedef __attribute__((ext_vector_type(8))) __bf16 bf16x8;

__device__ __forceinline__ unsigned short f2bf(float x) {
    union { float f; unsigned u; } v; v.f = x;
    unsigned r = v.u + 0x7fffu + ((v.u >> 16) & 1u);
    return (unsigned short)(r >> 16);
}

// ---------------- P1: M = out_proj_w @ Wv ; c = out_proj_w @ bv + out_proj_b ----------------
__global__ void p1_M_c(const float* __restrict__ out_proj_w,
                       const float* __restrict__ out_proj_b,
                       const float* __restrict__ in_proj_w,
                       const float* __restrict__ in_proj_b,
                       float* __restrict__ Mmat, float* __restrict__ cvec) {
    __shared__ float row[256];
    __shared__ float red[256];
    const int i = blockIdx.x, j = threadIdx.x;
    row[j] = out_proj_w[i * 256 + j];
    __syncthreads();
    const float* Wv = in_proj_w + 512 * 256;
    float acc = 0.f;
    #pragma unroll 8
    for (int k = 0; k < 256; ++k) acc = fmaf(row[k], Wv[k * 256 + j], acc);
    Mmat[i * 256 + j] = acc;
    red[j] = row[j] * in_proj_b[512 + j];
    __syncthreads();
    for (int s = 128; s > 0; s >>= 1) {
        if (j < s) red[j] += red[j + s];
        __syncthreads();
    }
    if (j == 0) cvec[i] = red[0] + out_proj_b[i];
}

// ---------------- P2: G[half] = W_fuse[:, half*256:+256] @ M ----------------
__global__ void p2_G(const float* __restrict__ W_fuse, const float* __restrict__ Mmat,
                     float* __restrict__ G) {
    __shared__ float row[256];
    const int b = blockIdx.x, j = threadIdx.x;
    const int half = b >> 8, i = b & 255;
    row[j] = W_fuse[i * 512 + half * 256 + j];
    __syncthreads();
    float acc = 0.f;
    #pragma unroll 8
    for (int k = 0; k < 256; ++k) acc = fmaf(row[k], Mmat[k * 256 + j], acc);
    G[half * 65536 + i * 256 + j] = acc;
}

// ---------------- P3: A = G @ W_src -> Wt (bf16, MFMA-B-fragment tiled) ; b_total ----------------
// Wt layout: for n-tile nt (16 n each), k-quant kq (32 k each): 64 lanes x 16B contiguous,
//   lane l = q*16 + (n&15) holds A[n][kq*32 + q*8 + j], j=0..7.
__global__ void p3_A(const float* __restrict__ G,
                     const float* __restrict__ W_img, const float* __restrict__ W_text,
                     const float* __restrict__ W_fuse,
                     const float* __restrict__ b_img, const float* __restrict__ b_text,
                     const float* __restrict__ b_fuse, const float* __restrict__ cvec,
                     unsigned short* __restrict__ Wt, float* __restrict__ b_total) {
    __shared__ float grow[4][256];
    __shared__ float red[256];
    const int b = blockIdx.x, j = threadIdx.x;
    const int half = b & 1;
    const int n0 = (b >> 1) * 4;
    const float* Gh = G + half * 65536;
    #pragma unroll
    for (int rr = 0; rr < 4; ++rr) grow[rr][j] = Gh[(n0 + rr) * 256 + j];
    __syncthreads();
    const float* Wsrc = half ? W_text : W_img;
    float acc0[4] = {0.f, 0.f, 0.f, 0.f}, acc1[4] = {0.f, 0.f, 0.f, 0.f};
    #pragma unroll 4
    for (int m = 0; m < 256; ++m) {
        float w0 = Wsrc[m * 512 + j];
        float w1 = Wsrc[m * 512 + 256 + j];
        #pragma unroll
        for (int rr = 0; rr < 4; ++rr) {
            float g = grow[rr][m];
            acc0[rr] = fmaf(g, w0, acc0[rr]);
            acc1[rr] = fmaf(g, w1, acc1[rr]);
        }
    }
    #pragma unroll
    for (int rr = 0; rr < 4; ++rr) {
        const int n = n0 + rr;
        const int nt = n >> 4, nl = n & 15;
        {
            const int kg = half * 512 + j;
            const int kq = kg >> 5, q = (kg >> 3) & 3, jj = kg & 7;
            Wt[((nt * 32 + kq) * 64 + q * 16 + nl) * 8 + jj] = f2bf(acc0[rr]);
        }
        {
            const int kg = half * 512 + 256 + j;
            const int kq = kg >> 5, q = (kg >> 3) & 3, jj = kg & 7;
            Wt[((nt * 32 + kq) * 64 + q * 16 + nl) * 8 + jj] = f2bf(acc1[rr]);
        }
    }
    if (half == 0) {
        const float* Gi = G;
        const float* Gt = G + 65536;
        for (int rr = 0; rr < 4; ++rr) {
            const int n = n0 + rr;
            red[j] = Gi[n * 256 + j] * b_img[j] + Gt[n * 256 + j] * b_text[j]
                   + (W_fuse[n * 512 + j] + W_fuse[n * 512 + 256 + j]) * cvec[j];
            __syncthreads();
            for (int s = 128; s > 0; s >>= 1) {
                if (j < s) red[j] += red[j + s];
                __syncthreads();
            }
            if (j == 0) b_total[n] = b_fuse[n] + red[0];
            __syncthreads();
        }
    }
}

// ---------------- Main: out = relu([img|txt] @ Wt^T + b_total), bf16 MFMA ----------------
__global__ __launch_bounds__(256, 2)
void fused_gemm(const float* __restrict__ Ximg, const float* __restrict__ Xtxt,
                const unsigned short* __restrict__ Wt,
                const float* __restrict__ b_total, float* __restrict__ out) {
    __shared__ unsigned short At[2][128 * 64];  // 2 x 16KB, XOR-swizzled chunks
    const int bid = blockIdx.x;
    const int rowtile = bid >> 1;
    const int cb = bid & 1;                     // column block (128 cols each)
    const int rowbase = rowtile * 128;
    const int t = threadIdx.x;
    const int lane = t & 63;
    const int wave = t >> 6;
    const int wr = wave >> 1, wc = wave & 1;    // 2x2 wave grid over 128x128
    const int ml = lane & 15, q = lane >> 4;
    const int xr = ml & 7;
    const int sr = t >> 4;                      // staging row 0..15 (+16*i)
    const int sc4 = t & 15;                     // staging float4 column
    const int ntbase = cb * 8 + wc * 4;

    floatx4 ld[8];
    floatx4 acc[4][4];
    #pragma unroll
    for (int a = 0; a < 4; ++a)
        #pragma unroll
        for (int bq = 0; bq < 4; ++bq) acc[a][bq] = (floatx4){0.f, 0.f, 0.f, 0.f};

    auto load_step = [&](int s) {
        const int kb = (s & 7) * 64;
        const float* X = (s < 8) ? Ximg : Xtxt;
        const float* src = X + (size_t)(rowbase + sr) * 512 + kb + sc4 * 4;
        #pragma unroll
        for (int i = 0; i < 8; ++i)
            ld[i] = *(const floatx4*)(src + (size_t)i * 16 * 512);
    };
    auto store_tile = [&](unsigned short* buf) {
        const int c = sc4 >> 1;
        const int hofs = (sc4 & 1) * 4;
        #pragma unroll
        for (int i = 0; i < 8; ++i) {
            const int r = sr + 16 * i;
            const int chunk = c ^ (r & 7);
            float2 p0; p0.x = ld[i].x; p0.y = ld[i].y;
            float2 p1; p1.x = ld[i].z; p1.y = ld[i].w;
            __hip_bfloat162 v0 = __float22bfloat162_rn(p0);
            __hip_bfloat162 v1 = __float22bfloat162_rn(p1);
            __hip_bfloat162* dst = (__hip_bfloat162*)(buf + r * 64 + chunk * 8 + hofs);
            dst[0] = v0;
            dst[1] = v1;
        }
    };
    auto compute_step = [&](const unsigned short* buf, int s) {
        #pragma unroll
        for (int koi = 0; koi < 2; ++koi) {
            bf16x8 af[4];
            #pragma unroll
            for (int mi = 0; mi < 4; ++mi) {
                const int r = wr * 64 + mi * 16 + ml;
                const int chunk = ((koi << 2) | q) ^ xr;
                af[mi] = *(const bf16x8*)(buf + r * 64 + chunk * 8);
            }
            const int kq = 2 * s + koi;
            bf16x8 bfr[4];
            #pragma unroll
            for (int ni = 0; ni < 4; ++ni)
                bfr[ni] = *(const bf16x8*)(Wt + (size_t)((ntbase + ni) * 32 + kq) * 512 + lane * 8);
            #pragma unroll
            for (int mi = 0; mi < 4; ++mi)
                #pragma unroll
                for (int ni = 0; ni < 4; ++ni)
                    acc[mi][ni] = __builtin_amdgcn_mfma_f32_16x16x32_bf16(af[mi], bfr[ni], acc[mi][ni], 0, 0, 0);
        }
    };

    load_step(0);
    store_tile(At[0]);
    for (int s = 0; s < 16; ++s) {
        __syncthreads();                 // buf[s&1] ready; buf[(s+1)&1] free
        if (s < 15) load_step(s + 1);    // HBM loads in flight during MFMA
        compute_step(At[s & 1], s);
        if (s < 15) store_tile(At[(s + 1) & 1]);
    }

    // epilogue: C/D layout col=lane&15, row=q*4+e
    const int colbase = cb * 128 + wc * 64;
    #pragma unroll
    for (int ni = 0; ni < 4; ++ni) {
        const int col = colbase + ni * 16 + ml;
        const float bias = b_total[col];
        #pragma unroll
        for (int mi = 0; mi < 4; ++mi) {
            const size_t r0 = (size_t)rowbase + wr * 64 + mi * 16 + q * 4;
            #pragma unroll
            for (int e = 0; e < 4; ++e) {
                float v = acc[mi][ni][e] + bias;
                out[(r0 + e) * 256 + col] = fmaxf(v, 0.f);
            }
        }
    }
}

extern "C" void kernel_launch(void* const* d_in, const int* in_sizes, int n_in,
                              void* d_out, int out_size, void* d_ws, size_t ws_size,
                              hipStream_t stream) {
    const float* text       = (const float*)d_in[0];
    const float* image      = (const float*)d_in[1];
    const float* W_text     = (const float*)d_in[2];
    const float* b_text     = (const float*)d_in[3];
    const float* W_img      = (const float*)d_in[4];
    const float* b_img      = (const float*)d_in[5];
    const float* in_proj_w  = (const float*)d_in[6];
    const float* in_proj_b  = (const float*)d_in[7];
    const float* out_proj_w = (const float*)d_in[8];
    const float* out_proj_b = (const float*)d_in[9];
    const float* W_fuse     = (const float*)d_in[10];
    const float* b_fuse     = (const float*)d_in[11];
    float* out = (float*)d_out;

    float* ws      = (float*)d_ws;
    float* Mmat    = ws;                      // 65536 f32
    float* G       = ws + 65536;              // 2*65536 f32
    float* cvec    = ws + 3 * 65536;          // 256 f32
    float* b_total = cvec + 256;              // 256 f32
    unsigned short* Wt = (unsigned short*)(b_total + 256);  // 262144 bf16

    p1_M_c<<<dim3(256), dim3(256), 0, stream>>>(out_proj_w, out_proj_b, in_proj_w, in_proj_b, Mmat, cvec);
    p2_G<<<dim3(512), dim3(256), 0, stream>>>(W_fuse, Mmat, G);
    p3_A<<<dim3(128), dim3(256), 0, stream>>>(G, W_img, W_text, W_fuse, b_img, b_text, b_fuse, cvec, Wt, b_total);
    fused_gemm<<<dim3(1024), dim3(256), 0, stream>>>(image, text, Wt, b_total, out);
}